// Round 1
// 616.835 us; speedup vs baseline: 1.1583x; 1.1583x over previous
//
#include <hip/hip_runtime.h>
#include <hip/hip_bf16.h>

// Problem sizes (fixed)
constexpr int B   = 256;
constexpr int M   = 2048;
constexpr int E   = 128;
constexpr int IN  = 512;
constexpr int Qd  = 512;
constexpr int OUTd= 512;
constexpr int H   = 64;

// Output element offsets (same element layout for bf16 or f32 outputs)
constexpr size_t OFF_WR = 0;
constexpr size_t OFF_W  = (size_t)B*M;
constexpr size_t OFF_U  = (size_t)2*B*M;
constexpr size_t OFF_Y  = (size_t)3*B*M;
constexpr size_t OFF_NM = OFF_Y + (size_t)B*OUTd;

// ---------- bf16 helpers ----------
__device__ __forceinline__ float bf2f(unsigned short u) {
    union { unsigned int i; float f; } v; v.i = ((unsigned int)u) << 16; return v.f;
}
__device__ __forceinline__ unsigned short f2bf(float f) {
    unsigned int x = __float_as_uint(f);
    unsigned int r = (x + 0x7fffu + ((x >> 16) & 1u)) >> 16;   // RNE
    return (unsigned short)r;
}
__device__ __forceinline__ void unpack8(uint4 d, float* o) {
    o[0]=bf2f(d.x & 0xffff); o[1]=bf2f(d.x >> 16);
    o[2]=bf2f(d.y & 0xffff); o[3]=bf2f(d.y >> 16);
    o[4]=bf2f(d.z & 0xffff); o[5]=bf2f(d.z >> 16);
    o[6]=bf2f(d.w & 0xffff); o[7]=bf2f(d.w >> 16);
}
__device__ __forceinline__ uint4 pack8(const float* f) {
    uint4 d;
    d.x = (unsigned)f2bf(f[0]) | ((unsigned)f2bf(f[1]) << 16);
    d.y = (unsigned)f2bf(f[2]) | ((unsigned)f2bf(f[3]) << 16);
    d.z = (unsigned)f2bf(f[4]) | ((unsigned)f2bf(f[5]) << 16);
    d.w = (unsigned)f2bf(f[6]) | ((unsigned)f2bf(f[7]) << 16);
    return d;
}

// ---------- dual-dtype load/store (bf = 1 -> bf16, 0 -> f32); wave-uniform branch ----------
__device__ __forceinline__ float ldf(const void* p, size_t i, int bf) {
    return bf ? bf2f(((const unsigned short*)p)[i]) : ((const float*)p)[i];
}
__device__ __forceinline__ void ld8(const void* p, size_t i, int bf, float* o) {
    if (bf) {
        uint4 d = *(const uint4*)((const unsigned short*)p + i);
        unpack8(d, o);
    } else {
        const float4* q = (const float4*)((const float*)p + i);
        float4 a = q[0], c = q[1];
        o[0]=a.x; o[1]=a.y; o[2]=a.z; o[3]=a.w;
        o[4]=c.x; o[5]=c.y; o[6]=c.z; o[7]=c.w;
    }
}
__device__ __forceinline__ void st1(void* p, size_t i, int bf, float v) {
    if (bf) ((unsigned short*)p)[i] = f2bf(v);
    else    ((float*)p)[i] = v;
}
__device__ __forceinline__ void st8(void* p, size_t i, int bf, const float* v) {
    if (bf) {
        *(uint4*)((unsigned short*)p + i) = pack8(v);
    } else {
        float4 a, c;
        a.x=v[0]; a.y=v[1]; a.z=v[2]; a.w=v[3];
        c.x=v[4]; c.y=v[5]; c.z=v[6]; c.w=v[7];
        float4* q = (float4*)((float*)p + i);
        q[0]=a; q[1]=c;
    }
}

// ---------- k0: dtype detector ----------
__global__ __launch_bounds__(512) void k0_detect(const void* usage, int* flag) {
    __shared__ int cnt;
    if (threadIdx.x == 0) cnt = 0;
    __syncthreads();
    float v = bf2f(((const unsigned short*)usage)[threadIdx.x]);
    int ok = (v >= 0.0f && v <= 1.0f) ? 1 : 0;
    atomicAdd(&cnt, ok);
    __syncthreads();
    if (threadIdx.x == 0) flag[0] = (cnt >= 500) ? 1 : 0;
}

// ---------- k1: per-batch small precompute, two independent chains on thread halves ----------
// chain A (t<128):  emb = I_w x + I_b; Wi = W1 emb + b; v = W2^T Wi; c1 = Wi.W2_b
// chain B (t>=128): Rq = R1 q + b;     u2 = R2^T Rq;    c2 = Rq.R2_b
// (d2 = u2.emb moved to k4)
__global__ __launch_bounds__(256) void k1_pre(
    const void* __restrict__ x,   const void* __restrict__ qy,
    const void* __restrict__ I_w, const void* __restrict__ I_b,
    const void* __restrict__ W1w, const void* __restrict__ W1b,
    const void* __restrict__ W2w, const void* __restrict__ W2b,
    const void* __restrict__ R1w, const void* __restrict__ R1b,
    const void* __restrict__ R2w, const void* __restrict__ R2b,
    const int* __restrict__ flag,
    float* __restrict__ emb_ws, float* __restrict__ v_ws, float* __restrict__ u2_ws,
    float* __restrict__ c1_ws,  float* __restrict__ c2_ws)
{
    const int bf = *flag;
    __shared__ float xs[IN], qs[Qd], embs[E], wis[H], rqs[H], red[256];
    const int b = blockIdx.x, t = threadIdx.x;

    for (int i = t; i < IN; i += 256) xs[i] = ldf(x,  (size_t)b*IN + i, bf);
    for (int i = t; i < Qd; i += 256) qs[i] = ldf(qy, (size_t)b*Qd + i, bf);
    __syncthreads();

    // phase 1: emb[t<128] || Rq[t2<64]
    if (t < 128) {
        float acc = 0.f;
        for (int c = 0; c < IN/8; ++c) {
            float m8[8]; ld8(I_w, (size_t)t*IN + c*8, bf, m8);
            #pragma unroll
            for (int j = 0; j < 8; ++j) acc += m8[j] * xs[c*8 + j];
        }
        acc += ldf(I_b, t, bf);
        embs[t] = acc;
        emb_ws[(size_t)b*E + t] = acc;
    } else {
        int t2 = t - 128;
        if (t2 < H) {
            float rv = 0.f;
            for (int c = 0; c < Qd/8; ++c) {
                float m8[8]; ld8(R1w, (size_t)t2*Qd + c*8, bf, m8);
                #pragma unroll
                for (int j = 0; j < 8; ++j) rv += m8[j] * qs[c*8 + j];
            }
            rv += ldf(R1b, t2, bf);
            rqs[t2] = rv;
        }
    }
    __syncthreads();

    // phase 2: Wi[t<64] || u2[t2<128] + c2 partials
    if (t < H) {
        float wv = 0.f;
        for (int c = 0; c < E/8; ++c) {
            float m8[8]; ld8(W1w, (size_t)t*E + c*8, bf, m8);
            #pragma unroll
            for (int j = 0; j < 8; ++j) wv += m8[j] * embs[c*8 + j];
        }
        wv += ldf(W1b, t, bf);
        wis[t] = wv;
    } else if (t >= 128) {
        int t2 = t - 128;
        float uu = 0.f;
        for (int h = 0; h < H; ++h) uu += ldf(R2w, (size_t)h*E + t2, bf) * rqs[h];
        u2_ws[(size_t)b*E + t2] = uu;
        red[t] = (t2 < H) ? rqs[t2] * ldf(R2b, t2, bf) : 0.f;
    }
    __syncthreads();

    // phase 3: v[t<128] + c1 partials
    if (t < 128) {
        float vv = 0.f;
        for (int h = 0; h < H; ++h) vv += ldf(W2w, (size_t)h*E + t, bf) * wis[h];
        v_ws[(size_t)b*E + t] = vv;
        red[t] = (t < H) ? wis[t] * ldf(W2b, t, bf) : 0.f;
    }
    __syncthreads();

    // dual half-reductions: red[0:128) -> c1, red[128:256) -> c2
    for (int off = 64; off > 0; off >>= 1) {
        if (t < off) red[t] += red[t + off];
        if (t >= 128 && t < 128 + off) red[t] += red[t + off];
        __syncthreads();
    }
    if (t == 0)   c1_ws[b] = red[0];
    if (t == 128) c2_ws[b] = red[128];
}

// ---------- kB: merged launch. blocks [0,B): allocation (in-register shuffle bitonic);
//                              blocks [B, B+16B): memory scores pass ----------
__global__ __launch_bounds__(256) void kB_alloc_scores(
    const void* __restrict__ rw, const void* __restrict__ ww,
    const void* __restrict__ us, const void* __restrict__ fg,
    const void* __restrict__ mem,
    const float* __restrict__ v_ws, const float* __restrict__ u2_ws,
    const float* __restrict__ c1_ws, const int* __restrict__ flag,
    float* __restrict__ alloc_ws, float* __restrict__ s1, float* __restrict__ s2,
    void* __restrict__ dout)
{
    __shared__ unsigned long long sh64[M];   // 16 KB, sort path only
    __shared__ float scan[256];
    const int bf = *flag;
    const int t = threadIdx.x;

    if (blockIdx.x < B) {
        // ================= allocation path =================
        const int b = blockIdx.x;
        const size_t base = (size_t)b*M + (size_t)t*8;
        float r8[8], w8[8], u8[8], f8[8], nu[8];
        ld8(rw, base, bf, r8); ld8(ww, base, bf, w8);
        ld8(us, base, bf, u8); ld8(fg, base, bf, f8);

        unsigned long long key[8];
        #pragma unroll
        for (int q = 0; q < 8; ++q) {
            float u = 1e-5f + (1.0f - 1e-5f) * u8[q];
            float psi = 1.0f - f8[q] * r8[q];
            u = u + w8[q] - u * w8[q];
            u = u * psi;
            nu[q] = u;
            // monotone float->uint map, stable composite key (bits<<32)|idx
            unsigned fb = __float_as_uint(u);
            fb = (fb & 0x80000000u) ? ~fb : (fb | 0x80000000u);
            key[q] = ((unsigned long long)fb << 32) | (unsigned)(t*8 + q);
        }
        st8(dout, OFF_U + base, bf, nu);          // new_usage output

        // Bitonic sort ascending on uint64 keys, 8 elems/thread (i = t*8+q)
        for (int k = 2; k <= M; k <<= 1) {
            for (int j = k >> 1; j > 0; j >>= 1) {
                if (j >= 512) {
                    // cross-wave exchange via LDS (only j=512,1024)
                    __syncthreads();
                    #pragma unroll
                    for (int q = 0; q < 8; ++q) sh64[t*8 + q] = key[q];
                    __syncthreads();
                    const bool up      = (((t << 3) & k) == 0);
                    const bool lower   = (((t << 3) & j) == 0);
                    const bool keepmin = (lower == up);
                    #pragma unroll
                    for (int q = 0; q < 8; ++q) {
                        unsigned long long o = sh64[(t*8 + q) ^ j];
                        bool take = keepmin ? (o < key[q]) : (o > key[q]);
                        if (take) key[q] = o;
                    }
                } else if (j >= 8) {
                    // in-wave butterfly via shfl_xor (lane distance d = j/8 <= 32)
                    const int d = j >> 3;
                    const bool up      = (((t << 3) & k) == 0);
                    const bool keepmin = (((t & d) == 0) == up);
                    #pragma unroll
                    for (int q = 0; q < 8; ++q) {
                        unsigned long long o = __shfl_xor(key[q], d, 64);
                        bool take = keepmin ? (o < key[q]) : (o > key[q]);
                        if (take) key[q] = o;
                    }
                } else {
                    // within-thread stages (j = 1,2,4)
                    #pragma unroll
                    for (int q = 0; q < 8; ++q) {
                        if (!(q & j)) {
                            int p = q | j;
                            bool up = ((((t << 3) + q) & k) == 0);
                            unsigned long long a = key[q], c = key[p];
                            bool sw = up ? (a > c) : (a < c);
                            if (sw) { key[q] = c; key[p] = a; }
                        }
                    }
                }
            }
        }

        // extract sorted (u, idx); inclusive cumprod; scatter alloc
        float su[8], lp[8]; int sidx[8];
        #pragma unroll
        for (int q = 0; q < 8; ++q) {
            unsigned fb = (unsigned)(key[q] >> 32);
            fb = (fb & 0x80000000u) ? (fb ^ 0x80000000u) : ~fb;
            su[q]   = __uint_as_float(fb);
            sidx[q] = (int)(key[q] & 0xffffffffu);
        }
        float run = 1.f;
        #pragma unroll
        for (int q = 0; q < 8; ++q) { run *= su[q]; lp[q] = run; }
        scan[t] = run;
        __syncthreads();
        for (int off = 1; off < 256; off <<= 1) {
            float val = scan[t];
            float oth = (t >= off) ? scan[t - off] : 1.0f;
            __syncthreads();
            scan[t] = val * oth;
            __syncthreads();
        }
        float pref = (t > 0) ? scan[t - 1] : 1.0f;
        #pragma unroll
        for (int q = 0; q < 8; ++q)
            alloc_ws[(size_t)b*M + sidx[q]] = (1.0f - su[q]) * (pref * lp[q]);

    } else {
        // ================= scores path: s1 = v.mem + c1, s2 = u2.mem =================
        const int blk = blockIdx.x - B;
        const int b = blk >> 4, chunk = blk & 15;
        const int l = t & 15, g = t >> 4;
        float v8[8], u8[8];
        {
            const float* vb = v_ws  + (size_t)b*E + l*8;
            const float* ub = u2_ws + (size_t)b*E + l*8;
            #pragma unroll
            for (int j = 0; j < 8; ++j) { v8[j] = vb[j]; u8[j] = ub[j]; }
        }
        const float cc1 = c1_ws[b];
        const size_t mbase = (size_t)b*M*E;
        const int row0 = chunk*128 + g;
        for (int it = 0; it < 8; ++it) {
            int row = row0 + it*16;
            float m8[8]; ld8(mem, mbase + (size_t)row*E + l*8, bf, m8);
            float p1 = 0.f, p2 = 0.f;
            #pragma unroll
            for (int j = 0; j < 8; ++j) { p1 += m8[j]*v8[j]; p2 += m8[j]*u8[j]; }
            #pragma unroll
            for (int mask = 8; mask > 0; mask >>= 1) {
                p1 += __shfl_xor(p1, mask, 16);
                p2 += __shfl_xor(p2, mask, 16);
            }
            if (l == 0) {
                s1[(size_t)b*M + row] = p1 + cc1;
                s2[(size_t)b*M + row] = p2;
            }
        }
    }
}

// ---------- k4: per-batch softmax chain -> w, wr (computes d2 = u2.emb locally) ----------
__global__ __launch_bounds__(256) void k4_weights(
    const float* __restrict__ s1, const float* __restrict__ s2,
    const float* __restrict__ alloc_ws,
    const float* __restrict__ c2_ws,
    const float* __restrict__ u2_ws, const float* __restrict__ emb_ws,
    const int* __restrict__ flag,
    float* __restrict__ w_ws, float* __restrict__ wr_ws,
    void* __restrict__ dout)
{
    const int bf = *flag;
    __shared__ float red[256];
    const int b = blockIdx.x, t = threadIdx.x;
    const float* s1b = s1 + (size_t)b*M;
    const float* s2b = s2 + (size_t)b*M;

    // d2 = dot(u2, emb) over E=128
    red[t] = (t < E) ? u2_ws[(size_t)b*E + t] * emb_ws[(size_t)b*E + t] : 0.f;
    __syncthreads();
    for (int off = 128; off > 0; off >>= 1) { if (t < off) red[t] += red[t+off]; __syncthreads(); }
    const float dd = red[0];
    const float cc = c2_ws[b];
    __syncthreads();

    float sv[8];
    float lmax = -3.4e38f;
    #pragma unroll
    for (int s = 0; s < 8; ++s) { sv[s] = s1b[s*256 + t]; lmax = fmaxf(lmax, sv[s]); }
    red[t] = lmax; __syncthreads();
    for (int off = 128; off > 0; off >>= 1) { if (t < off) red[t] = fmaxf(red[t], red[t+off]); __syncthreads(); }
    float gmax = red[0]; __syncthreads();

    float lsum = 0.f;
    #pragma unroll
    for (int s = 0; s < 8; ++s) { float e = expf(sv[s] - gmax); sv[s] = e; lsum += e; }
    red[t] = lsum; __syncthreads();
    for (int off = 128; off > 0; off >>= 1) { if (t < off) red[t] += red[t+off]; __syncthreads(); }
    float inv = 1.0f / red[0]; __syncthreads();

    float rs[8];
    #pragma unroll
    for (int s = 0; s < 8; ++s) {
        int m = s*256 + t;
        float wc = sv[s] * inv;
        float wv = 0.5f * (wc + alloc_ws[(size_t)b*M + m]);
        w_ws[(size_t)b*M + m] = wv;
        st1(dout, OFF_W + (size_t)b*M + m, bf, wv);   // new_write_weights
        rs[s] = s2b[m] + wv * dd + cc;
    }

    lmax = -3.4e38f;
    #pragma unroll
    for (int s = 0; s < 8; ++s) lmax = fmaxf(lmax, rs[s]);
    red[t] = lmax; __syncthreads();
    for (int off = 128; off > 0; off >>= 1) { if (t < off) red[t] = fmaxf(red[t], red[t+off]); __syncthreads(); }
    gmax = red[0]; __syncthreads();

    lsum = 0.f;
    #pragma unroll
    for (int s = 0; s < 8; ++s) { float e = expf(rs[s] - gmax); rs[s] = e; lsum += e; }
    red[t] = lsum; __syncthreads();
    for (int off = 128; off > 0; off >>= 1) { if (t < off) red[t] += red[t+off]; __syncthreads(); }
    float inv2 = 1.0f / red[0]; __syncthreads();

    #pragma unroll
    for (int s = 0; s < 8; ++s) {
        int m = s*256 + t;
        float wrv = rs[s] * inv2;
        wr_ws[(size_t)b*M + m] = wrv;
        st1(dout, OFF_WR + (size_t)b*M + m, bf, wrv); // wr
    }
}

// ---------- k5: new_mem = mem + w*emb (store), per-chunk pooled partials (no atomics) ----------
__global__ __launch_bounds__(256) void k5_update(
    const void* __restrict__ mem, const float* __restrict__ emb_ws,
    const float* __restrict__ w_ws, const float* __restrict__ wr_ws,
    const int* __restrict__ flag,
    void* __restrict__ dout, float* __restrict__ pooled_p)
{
    const int bf = *flag;
    __shared__ float pw[4][E];
    const int blk = blockIdx.x;
    const int b = blk >> 4, chunk = blk & 15;
    const int t = threadIdx.x, l = t & 15, g = t >> 4;

    float e8[8];
    {
        const float* eb = emb_ws + (size_t)b*E + l*8;
        #pragma unroll
        for (int j = 0; j < 8; ++j) e8[j] = eb[j];
    }
    float acc[8] = {0,0,0,0,0,0,0,0};
    const size_t mbase = (size_t)b*M*E;
    const int row0 = chunk*128 + g;
    for (int it = 0; it < 8; ++it) {
        int row = row0 + it*16;
        size_t off = mbase + (size_t)row*E + l*8;
        float m8[8]; ld8(mem, off, bf, m8);
        float wv  = w_ws [(size_t)b*M + row];
        float wrv = wr_ws[(size_t)b*M + row];
        float n8[8];
        #pragma unroll
        for (int j = 0; j < 8; ++j) {
            n8[j] = m8[j] + wv * e8[j];
            acc[j] += wrv * n8[j];
        }
        st8(dout, OFF_NM + off, bf, n8);          // new_memory output
    }
    // reduce over the 16 g-groups: 4 in-wave via shfl, 4 waves via LDS
    #pragma unroll
    for (int j = 0; j < 8; ++j) {
        acc[j] += __shfl_xor(acc[j], 16, 64);
        acc[j] += __shfl_xor(acc[j], 32, 64);
    }
    const int wid = t >> 6;
    if ((t & 63) < 16) {
        const int l0 = t & 15;
        #pragma unroll
        for (int j = 0; j < 8; ++j) pw[wid][l0*8 + j] = acc[j];
    }
    __syncthreads();
    if (t < E)
        pooled_p[((size_t)b*16 + chunk)*E + t] = pw[0][t] + pw[1][t] + pw[2][t] + pw[3][t];
}

// ---------- k6: pooled = sum chunks; output = pooled @ O_w^T + O_b ----------
__global__ __launch_bounds__(256) void k6_out(
    const float* __restrict__ pooled_p,
    const void* __restrict__ O_w, const void* __restrict__ O_b,
    const int* __restrict__ flag,
    void* __restrict__ dout)
{
    const int bf = *flag;
    __shared__ float ps[E];
    const int b = blockIdx.x, t = threadIdx.x;
    if (t < E) {
        float s = 0.f;
        #pragma unroll
        for (int c = 0; c < 16; ++c) s += pooled_p[((size_t)b*16 + c)*E + t];
        ps[t] = s;
    }
    __syncthreads();
    for (int o = t; o < OUTd; o += 256) {
        float acc = 0.f;
        for (int c = 0; c < E/8; ++c) {
            float m8[8]; ld8(O_w, (size_t)o*E + c*8, bf, m8);
            #pragma unroll
            for (int j = 0; j < 8; ++j) acc += m8[j] * ps[c*8 + j];
        }
        acc += ldf(O_b, o, bf);
        st1(dout, OFF_Y + (size_t)b*OUTd + o, bf, acc);
    }
}

extern "C" void kernel_launch(void* const* d_in, const int* in_sizes, int n_in,
                              void* d_out, int out_size, void* d_ws, size_t ws_size,
                              hipStream_t stream)
{
    const void* rw  = d_in[0];
    const void* ww  = d_in[1];
    const void* us  = d_in[2];
    const void* fg  = d_in[3];
    const void* x   = d_in[4];
    const void* qy  = d_in[5];
    const void* mem = d_in[6];
    const void* I_w = d_in[7];
    const void* I_b = d_in[8];
    const void* W1w = d_in[9];
    const void* W1b = d_in[10];
    const void* W2w = d_in[11];
    const void* W2b = d_in[12];
    const void* R1w = d_in[13];
    const void* R1b = d_in[14];
    const void* R2w = d_in[15];
    const void* R2b = d_in[16];
    const void* O_w = d_in[17];
    const void* O_b = d_in[18];

    int*   flag_ws = (int*)d_ws;
    float* fbase   = (float*)d_ws + 16;               // 64B offset, keep alignment
    float* emb_ws   = fbase;                          // B*E
    float* v_ws     = emb_ws + (size_t)B*E;           // B*E
    float* u2_ws    = v_ws   + (size_t)B*E;           // B*E
    float* c1_ws    = u2_ws  + (size_t)B*E;           // B
    float* c2_ws    = c1_ws  + B;                     // B
    float* alloc_ws = c2_ws  + B;                     // B*M (reused as pooled_p after k4)
    float* s1_ws    = alloc_ws + (size_t)B*M;         // B*M
    float* s2_ws    = s1_ws    + (size_t)B*M;         // B*M
    float* w_ws     = s2_ws    + (size_t)B*M;         // B*M
    float* wr_ws    = w_ws     + (size_t)B*M;         // B*M
    float* pooled_p = alloc_ws;                       // B*16*E == B*M floats, alloc dead after k4

    k0_detect<<<1,        512, 0, stream>>>(us, flag_ws);
    k1_pre   <<<B,        256, 0, stream>>>(x, qy, I_w, I_b, W1w, W1b, W2w, W2b,
                                            R1w, R1b, R2w, R2b, flag_ws,
                                            emb_ws, v_ws, u2_ws, c1_ws, c2_ws);
    kB_alloc_scores<<<B + B*16, 256, 0, stream>>>(rw, ww, us, fg, mem,
                                            v_ws, u2_ws, c1_ws, flag_ws,
                                            alloc_ws, s1_ws, s2_ws, d_out);
    k4_weights<<<B,       256, 0, stream>>>(s1_ws, s2_ws, alloc_ws, c2_ws,
                                            u2_ws, emb_ws, flag_ws,
                                            w_ws, wr_ws, d_out);
    k5_update<<<B*16,     256, 0, stream>>>(mem, emb_ws, w_ws, wr_ws, flag_ws,
                                            d_out, pooled_p);
    k6_out   <<<B,        256, 0, stream>>>(pooled_p, O_w, O_b, flag_ws, d_out);
}